// Round 1
// baseline (8524.849 us; speedup 1.0000x reference)
//
#include <hip/hip_runtime.h>

#define B_ 64
#define S_ 128
#define H_ 512
#define E_ 512
#define V_ 32000
#define T_ 30
#define KX_ 1536   // E + 2H  (GRU input  [emb|ctx])
#define KF_ 2048   // E + 3H  (fc  input  [emb|h|ctx])

typedef float f32x4 __attribute__((ext_vector_type(4)));
typedef short s16x8 __attribute__((ext_vector_type(8)));
typedef short s16x4 __attribute__((ext_vector_type(4)));

__device__ __forceinline__ short f2bf(float f) {
  union { float f; unsigned u; } v; v.f = f;
  unsigned r = v.u + 0x7fffu + ((v.u >> 16) & 1u);
  return (short)(r >> 16);
}

__device__ __forceinline__ f32x4 mfma16(s16x8 a, s16x8 b, f32x4 c) {
  return __builtin_amdgcn_mfma_f32_16x16x32_bf16(a, b, c, 0, 0, 0);
}

// ---------------------------------------------------------------- cvt fp32->bf16
__global__ __launch_bounds__(256) void cvt_bf16_kernel(const float* __restrict__ src,
                                                       short* __restrict__ dst, int n4) {
  int i = blockIdx.x * 256 + threadIdx.x;
  if (i >= n4) return;
  f32x4 v = *(const f32x4*)(src + (size_t)i * 4);
  s16x4 o;
  o[0] = f2bf(v[0]); o[1] = f2bf(v[1]); o[2] = f2bf(v[2]); o[3] = f2bf(v[3]);
  *(s16x4*)(dst + (size_t)i * 4) = o;
}

// ---------------------------------------------------------------- init hidden
__global__ __launch_bounds__(256) void init_kernel(const float* __restrict__ ehid,
                                                   float* __restrict__ hidden,
                                                   short* __restrict__ xg) {
  int i = blockIdx.x * 256 + threadIdx.x;   // 32768
  float h = ehid[i];
  hidden[i] = h;
  int b = i >> 9, hh = i & 511;
  xg[b * 2048 + 1536 + hh] = f2bf(h);
}

// ---------------------------------------------------------------- enc_ua = enc @ ua^T  (M=8192,N=512,K=1024), fp32 in, fp32 out, bf16 MFMA
__global__ __launch_bounds__(256) void enc_ua_kernel(const float* __restrict__ enc,
                                                     const float* __restrict__ ua,
                                                     float* __restrict__ enc_ua) {
  __shared__ short alds[64 * 264];
  int tid = threadIdx.x;
  int wv = tid >> 6, lane = tid & 63;
  int q = lane >> 4, ml = lane & 15;
  int m0 = blockIdx.x * 64;                 // 128 m-blocks
  int n0 = blockIdx.y * 128 + wv * 32;      // 4 n-blocks
  f32x4 acc[4][2];
  f32x4 zz = {0.f, 0.f, 0.f, 0.f};
#pragma unroll
  for (int a = 0; a < 4; a++) { acc[a][0] = zz; acc[a][1] = zz; }

  for (int kc = 0; kc < 4; kc++) {          // K chunks of 256
    __syncthreads();
    for (int i = tid; i < 4096; i += 256) { // 64 rows x 64 float4
      int m = i >> 6, kk = (i & 63) << 2;
      f32x4 v = *(const f32x4*)(enc + (size_t)(m0 + m) * 1024 + kc * 256 + kk);
      s16x4 o;
      o[0] = f2bf(v[0]); o[1] = f2bf(v[1]); o[2] = f2bf(v[2]); o[3] = f2bf(v[3]);
      *(s16x4*)(&alds[m * 264 + kk]) = o;
    }
    __syncthreads();
#pragma unroll
    for (int kt = 0; kt < 8; kt++) {
      int k = kt * 32 + q * 8;
      int gk = kc * 256 + k;
      s16x8 bf[2];
#pragma unroll
      for (int nf = 0; nf < 2; nf++) {
        const float* bp = ua + (size_t)(n0 + nf * 16 + ml) * 1024 + gk;
        f32x4 b0 = *(const f32x4*)bp, b1 = *(const f32x4*)(bp + 4);
        s16x8 t;
        t[0] = f2bf(b0[0]); t[1] = f2bf(b0[1]); t[2] = f2bf(b0[2]); t[3] = f2bf(b0[3]);
        t[4] = f2bf(b1[0]); t[5] = f2bf(b1[1]); t[6] = f2bf(b1[2]); t[7] = f2bf(b1[3]);
        bf[nf] = t;
      }
#pragma unroll
      for (int mt = 0; mt < 4; mt++) {
        s16x8 af = *(const s16x8*)(&alds[(mt * 16 + ml) * 264 + k]);
        acc[mt][0] = mfma16(af, bf[0], acc[mt][0]);
        acc[mt][1] = mfma16(af, bf[1], acc[mt][1]);
      }
    }
  }
#pragma unroll
  for (int nf = 0; nf < 2; nf++) {
    int n = n0 + nf * 16 + ml;
#pragma unroll
    for (int mt = 0; mt < 4; mt++)
#pragma unroll
      for (int r = 0; r < 4; r++) {
        int m = m0 + mt * 16 + q * 4 + r;
        enc_ua[(size_t)m * 512 + n] = acc[mt][nf][r];
      }
  }
}

// ---------------------------------------------------------------- fused attention (one block per batch row)
__global__ __launch_bounds__(256) void attn_kernel(const float* __restrict__ hidden,
                                                   const float* __restrict__ wa,
                                                   const float* __restrict__ va,
                                                   const float* __restrict__ enc_ua,
                                                   const float* __restrict__ enc,
                                                   const float* __restrict__ embedding,
                                                   const int* __restrict__ target,
                                                   short* __restrict__ xg,
                                                   short* __restrict__ xf, int t) {
  int b = blockIdx.x, tid = threadIdx.x;
  __shared__ float hid[512];
  __shared__ float qv[512];
  __shared__ float sc[128];
  __shared__ float sred[128];

  for (int i = tid; i < 512; i += 256) hid[i] = hidden[b * 512 + i];

  // teacher-forced token, gather embedding -> xg[0:512], xf[0:512]
  int tok = (t == 0) ? 2 : target[b * 30 + (t - 1)];
  for (int i = tid; i < 512; i += 256) {
    short s = f2bf(embedding[(size_t)tok * 512 + i]);
    xg[b * 2048 + i] = s;
    xf[b * 2048 + i] = s;
  }
  __syncthreads();

  // q[h] = sum_k hid[k] * wa[h,k]
  for (int h = tid; h < 512; h += 256) {
    const f32x4* w = (const f32x4*)(wa + (size_t)h * 512);
    float a = 0.f;
#pragma unroll 4
    for (int k4 = 0; k4 < 128; k4++) {
      f32x4 wv = w[k4];
      f32x4 hv = *(const f32x4*)(hid + k4 * 4);
      a += wv[0] * hv[0] + wv[1] * hv[1] + wv[2] * hv[2] + wv[3] * hv[3];
    }
    qv[h] = a;
  }
  __syncthreads();

  // scores[s] = sum_h tanh(q[h] + enc_ua[b,s,h]) * va[h]   (wave per s)
  int wave = tid >> 6, lane = tid & 63;
  for (int s = wave; s < 128; s += 4) {
    const float* eu = enc_ua + ((size_t)b * 128 + s) * 512;
    float a = 0.f;
    for (int h = lane; h < 512; h += 64) {
      float e = qv[h] + eu[h];
      float ex = __expf(2.f * e);
      float th = 1.f - 2.f / (ex + 1.f);
      a += th * va[h];
    }
#pragma unroll
    for (int off = 32; off > 0; off >>= 1) a += __shfl_down(a, off);
    if (lane == 0) sc[s] = a;
  }
  __syncthreads();

  // softmax over 128
  if (tid < 128) sred[tid] = sc[tid];
  __syncthreads();
  for (int st = 64; st >= 1; st >>= 1) {
    if (tid < st) sred[tid] = fmaxf(sred[tid], sred[tid + st]);
    __syncthreads();
  }
  float mx = sred[0];
  __syncthreads();
  if (tid < 128) { float e = __expf(sc[tid] - mx); sc[tid] = e; sred[tid] = e; }
  __syncthreads();
  for (int st = 64; st >= 1; st >>= 1) {
    if (tid < st) sred[tid] += sred[tid + st];
    __syncthreads();
  }
  float inv = 1.f / sred[0];
  if (tid < 128) sc[tid] *= inv;
  __syncthreads();

  // context[d] = sum_s attw[s] * enc[b,s,d] -> xg[512+d], xf[1024+d]
  for (int d = tid; d < 1024; d += 256) {
    const float* ep = enc + (size_t)b * 128 * 1024 + d;
    float a = 0.f;
#pragma unroll 4
    for (int s = 0; s < 128; s++) a += sc[s] * ep[(size_t)s * 1024];
    short c = f2bf(a);
    xg[b * 2048 + 512 + d] = c;
    xf[b * 2048 + 1024 + d] = c;
  }
}

// ---------------------------------------------------------------- GRU GEMMs: gi = xg[:, :1536] @ w_ih^T ; gh = xg[:,1536:] @ w_hh^T
__global__ __launch_bounds__(256) void gru_gemm_kernel(const short* __restrict__ xg,
                                                       const short* __restrict__ wihb,
                                                       const short* __restrict__ whhb,
                                                       float* __restrict__ gi,
                                                       float* __restrict__ gh) {
  int tid = threadIdx.x;
  int wv = tid >> 6, lane = tid & 63;
  int q = lane >> 4, ml = lane & 15;
  int n = blockIdx.x * 64 + wv * 16 + ml;   // 24 blocks -> 1536
  f32x4 acci[4], acch[4];
  f32x4 zz = {0.f, 0.f, 0.f, 0.f};
#pragma unroll
  for (int a = 0; a < 4; a++) { acci[a] = zz; acch[a] = zz; }

  for (int kt = 0; kt < 48; kt++) {         // K = 1536
    int k = kt * 32 + q * 8;
    s16x8 bfrag = *(const s16x8*)(wihb + (size_t)n * 1536 + k);
#pragma unroll
    for (int mt = 0; mt < 4; mt++) {
      s16x8 af = *(const s16x8*)(xg + (size_t)(mt * 16 + ml) * 2048 + k);
      acci[mt] = mfma16(af, bfrag, acci[mt]);
    }
  }
  for (int kt = 0; kt < 16; kt++) {         // K = 512 (hidden)
    int k = kt * 32 + q * 8;
    s16x8 bfrag = *(const s16x8*)(whhb + (size_t)n * 512 + k);
#pragma unroll
    for (int mt = 0; mt < 4; mt++) {
      s16x8 af = *(const s16x8*)(xg + (size_t)(mt * 16 + ml) * 2048 + 1536 + k);
      acch[mt] = mfma16(af, bfrag, acch[mt]);
    }
  }
#pragma unroll
  for (int mt = 0; mt < 4; mt++)
#pragma unroll
    for (int r = 0; r < 4; r++) {
      int b = mt * 16 + q * 4 + r;
      gi[(size_t)b * 1536 + n] = acci[mt][r];
      gh[(size_t)b * 1536 + n] = acch[mt][r];
    }
}

// ---------------------------------------------------------------- gates (fp32)
__global__ __launch_bounds__(256) void gates_kernel(const float* __restrict__ gi,
                                                    const float* __restrict__ gh,
                                                    const float* __restrict__ bih,
                                                    const float* __restrict__ bhh,
                                                    float* __restrict__ hidden,
                                                    short* __restrict__ xg,
                                                    short* __restrict__ xf) {
  int i = blockIdx.x * 256 + threadIdx.x;   // 32768
  int b = i >> 9, h = i & 511;
  const float* gib = gi + (size_t)b * 1536;
  const float* ghb = gh + (size_t)b * 1536;
  float ir = gib[h] + bih[h];
  float iz = gib[512 + h] + bih[512 + h];
  float in_ = gib[1024 + h] + bih[1024 + h];
  float hr = ghb[h] + bhh[h];
  float hz = ghb[512 + h] + bhh[512 + h];
  float hn = ghb[1024 + h] + bhh[1024 + h];
  float r = 1.f / (1.f + __expf(-(ir + hr)));
  float z = 1.f / (1.f + __expf(-(iz + hz)));
  float nx = in_ + r * hn;
  float ex = __expf(2.f * nx);
  float n = 1.f - 2.f / (ex + 1.f);
  float hnew = (1.f - z) * n + z * hidden[i];
  hidden[i] = hnew;
  short hb = f2bf(hnew);
  xg[b * 2048 + 1536 + h] = hb;
  xf[b * 2048 + 512 + h] = hb;
}

// ---------------------------------------------------------------- fc: logits = xf @ fc_w^T + fc_b  (M=64,N=32000,K=2048)
template <bool PRE>
__global__ __launch_bounds__(256) void fc_kernel(const short* __restrict__ xf,
                                                 const short* __restrict__ fcwb,
                                                 const float* __restrict__ fcwf,
                                                 const float* __restrict__ fcb,
                                                 float* __restrict__ out, int t) {
  __shared__ short alds[64 * 264];
  int tid = threadIdx.x;
  int wv = tid >> 6, lane = tid & 63;
  int q = lane >> 4, ml = lane & 15;
  int n0 = blockIdx.x * 128 + wv * 32;      // 250 blocks
  f32x4 acc[4][2];
  f32x4 zz = {0.f, 0.f, 0.f, 0.f};
#pragma unroll
  for (int a = 0; a < 4; a++) { acc[a][0] = zz; acc[a][1] = zz; }

  for (int kc = 0; kc < 8; kc++) {          // K chunks of 256
    __syncthreads();
    for (int i = tid; i < 2048; i += 256) { // 64 rows x 32 x (8 bf16)
      int m = i >> 5, kk = (i & 31) << 3;
      *(s16x8*)(&alds[m * 264 + kk]) = *(const s16x8*)(xf + (size_t)m * 2048 + kc * 256 + kk);
    }
    __syncthreads();
#pragma unroll
    for (int kt = 0; kt < 8; kt++) {
      int k = kt * 32 + q * 8;
      int gk = kc * 256 + k;
      s16x8 bf0, bf1;
      if (PRE) {
        bf0 = *(const s16x8*)(fcwb + (size_t)(n0 + ml) * 2048 + gk);
        bf1 = *(const s16x8*)(fcwb + (size_t)(n0 + 16 + ml) * 2048 + gk);
      } else {
        const float* p0 = fcwf + (size_t)(n0 + ml) * 2048 + gk;
        const float* p1 = fcwf + (size_t)(n0 + 16 + ml) * 2048 + gk;
        f32x4 a0 = *(const f32x4*)p0, a1 = *(const f32x4*)(p0 + 4);
        f32x4 b0 = *(const f32x4*)p1, b1 = *(const f32x4*)(p1 + 4);
        bf0[0] = f2bf(a0[0]); bf0[1] = f2bf(a0[1]); bf0[2] = f2bf(a0[2]); bf0[3] = f2bf(a0[3]);
        bf0[4] = f2bf(a1[0]); bf0[5] = f2bf(a1[1]); bf0[6] = f2bf(a1[2]); bf0[7] = f2bf(a1[3]);
        bf1[0] = f2bf(b0[0]); bf1[1] = f2bf(b0[1]); bf1[2] = f2bf(b0[2]); bf1[3] = f2bf(b0[3]);
        bf1[4] = f2bf(b1[0]); bf1[5] = f2bf(b1[1]); bf1[6] = f2bf(b1[2]); bf1[7] = f2bf(b1[3]);
      }
#pragma unroll
      for (int mt = 0; mt < 4; mt++) {
        s16x8 af = *(const s16x8*)(&alds[(mt * 16 + ml) * 264 + k]);
        acc[mt][0] = mfma16(af, bf0, acc[mt][0]);
        acc[mt][1] = mfma16(af, bf1, acc[mt][1]);
      }
    }
  }
#pragma unroll
  for (int nf = 0; nf < 2; nf++) {
    int v = n0 + nf * 16 + ml;
    float bias = fcb[v];
#pragma unroll
    for (int mt = 0; mt < 4; mt++)
#pragma unroll
      for (int r = 0; r < 4; r++) {
        int b = mt * 16 + q * 4 + r;
        out[((size_t)b * T_ + t) * V_ + v] = acc[mt][nf][r] + bias;
      }
  }
}

// ---------------------------------------------------------------- per-step log_softmax over V (rows (b,t) L2-hot)
__global__ __launch_bounds__(256) void finalize_kernel(float* __restrict__ out, int t) {
  int b = blockIdx.x, tid = threadIdx.x;
  float* row = out + ((size_t)b * T_ + t) * V_;
  __shared__ float red[256];
  float mx = -3.4e38f;
  for (int i = tid; i < 8000; i += 256) {
    f32x4 v = *(const f32x4*)(row + i * 4);
    mx = fmaxf(mx, fmaxf(fmaxf(v[0], v[1]), fmaxf(v[2], v[3])));
  }
  red[tid] = mx; __syncthreads();
  for (int st = 128; st >= 1; st >>= 1) {
    if (tid < st) red[tid] = fmaxf(red[tid], red[tid + st]);
    __syncthreads();
  }
  mx = red[0]; __syncthreads();
  float sm = 0.f;
  for (int i = tid; i < 8000; i += 256) {
    f32x4 v = *(const f32x4*)(row + i * 4);
    sm += __expf(v[0] - mx) + __expf(v[1] - mx) + __expf(v[2] - mx) + __expf(v[3] - mx);
  }
  red[tid] = sm; __syncthreads();
  for (int st = 128; st >= 1; st >>= 1) {
    if (tid < st) red[tid] += red[tid + st];
    __syncthreads();
  }
  float lse = mx + __logf(red[0]);
  for (int i = tid; i < 8000; i += 256) {
    f32x4 v = *(const f32x4*)(row + i * 4);
    v[0] -= lse; v[1] -= lse; v[2] -= lse; v[3] -= lse;
    *(f32x4*)(row + i * 4) = v;
  }
}

// ================================================================ host
extern "C" void kernel_launch(void* const* d_in, const int* in_sizes, int n_in,
                              void* d_out, int out_size, void* d_ws, size_t ws_size,
                              hipStream_t stream) {
  const float* enc  = (const float*)d_in[0];
  const float* ehid = (const float*)d_in[1];
  const int*   tgt  = (const int*)  d_in[2];
  const float* emb  = (const float*)d_in[3];
  const float* wa   = (const float*)d_in[4];
  const float* ua   = (const float*)d_in[5];
  const float* va   = (const float*)d_in[6];
  const float* wih  = (const float*)d_in[7];
  const float* whh  = (const float*)d_in[8];
  const float* bih  = (const float*)d_in[9];
  const float* bhh  = (const float*)d_in[10];
  const float* fcw  = (const float*)d_in[11];
  const float* fcb  = (const float*)d_in[12];
  float* out = (float*)d_out;

  const size_t SZ_FCWB = (size_t)V_ * KF_ * 2;   // 131,072,000 B
  char* ws = (char*)d_ws;
  size_t off = 0;
  auto take = [&](size_t bytes) -> char* {
    char* p = ws + off;
    off = (off + bytes + 255) & ~(size_t)255;
    return p;
  };
  // small-buffer footprint
  size_t small_need;
  {
    size_t o = 0;
    auto sim = [&](size_t bb) { o = (o + bb + 255) & ~(size_t)255; };
    sim((size_t)B_ * S_ * H_ * 4);  // enc_ua
    sim((size_t)3 * H_ * KX_ * 2);  // wihb
    sim((size_t)3 * H_ * H_ * 2);   // whhb
    sim((size_t)B_ * H_ * 4);       // hidden
    sim((size_t)B_ * KF_ * 2);      // xg
    sim((size_t)B_ * KF_ * 2);      // xf
    sim((size_t)B_ * 3 * H_ * 4);   // gi
    sim((size_t)B_ * 3 * H_ * 4);   // gh
    small_need = o;
  }
  bool PRE = ws_size >= SZ_FCWB + small_need + 512;

  short* fcwb = nullptr;
  if (PRE) fcwb = (short*)take(SZ_FCWB);
  float* enc_ua = (float*)take((size_t)B_ * S_ * H_ * 4);
  short* wihb   = (short*)take((size_t)3 * H_ * KX_ * 2);
  short* whhb   = (short*)take((size_t)3 * H_ * H_ * 2);
  float* hidden = (float*)take((size_t)B_ * H_ * 4);
  short* xg     = (short*)take((size_t)B_ * KF_ * 2);
  short* xf     = (short*)take((size_t)B_ * KF_ * 2);
  float* gi     = (float*)take((size_t)B_ * 3 * H_ * 4);
  float* gh     = (float*)take((size_t)B_ * 3 * H_ * 4);

  if (PRE)
    cvt_bf16_kernel<<<(V_ * KF_ / 4 + 255) / 256, 256, 0, stream>>>(fcw, fcwb, V_ * KF_ / 4);
  cvt_bf16_kernel<<<(3 * H_ * KX_ / 4 + 255) / 256, 256, 0, stream>>>(wih, wihb, 3 * H_ * KX_ / 4);
  cvt_bf16_kernel<<<(3 * H_ * H_ / 4 + 255) / 256, 256, 0, stream>>>(whh, whhb, 3 * H_ * H_ / 4);
  init_kernel<<<(B_ * H_) / 256, 256, 0, stream>>>(ehid, hidden, xg);
  enc_ua_kernel<<<dim3(128, 4), 256, 0, stream>>>(enc, ua, enc_ua);

  for (int t = 0; t < T_; t++) {
    attn_kernel<<<B_, 256, 0, stream>>>(hidden, wa, va, enc_ua, enc, emb, tgt, xg, xf, t);
    gru_gemm_kernel<<<24, 256, 0, stream>>>(xg, wihb, whhb, gi, gh);
    gates_kernel<<<(B_ * H_) / 256, 256, 0, stream>>>(gi, gh, bih, bhh, hidden, xg, xf);
    if (PRE)
      fc_kernel<true><<<V_ / 128, 256, 0, stream>>>(xf, fcwb, fcw, fcb, out, t);
    else
      fc_kernel<false><<<V_ / 128, 256, 0, stream>>>(xf, fcwb, fcw, fcb, out, t);
    finalize_kernel<<<B_, 256, 0, stream>>>(out, t);
  }
}

// Round 2
// 4722.553 us; speedup vs baseline: 1.8051x; 1.8051x over previous
//
#include <hip/hip_runtime.h>

#define B_ 64
#define S_ 128
#define H_ 512
#define E_ 512
#define V_ 32000
#define T_ 30
#define KX_ 1536   // E + 2H  (GRU input  [emb|ctx])
#define KF_ 2048   // E + 3H  (fc  input  [emb|h|ctx])

typedef float f32x4 __attribute__((ext_vector_type(4)));
typedef short s16x8 __attribute__((ext_vector_type(8)));
typedef short s16x4 __attribute__((ext_vector_type(4)));

__device__ __forceinline__ short f2bf(float f) {
  union { float f; unsigned u; } v; v.f = f;
  unsigned r = v.u + 0x7fffu + ((v.u >> 16) & 1u);
  return (short)(r >> 16);
}
__device__ __forceinline__ float bf2f(short s) {
  union { unsigned u; float f; } v; v.u = ((unsigned)(unsigned short)s) << 16;
  return v.f;
}

__device__ __forceinline__ f32x4 mfma16(s16x8 a, s16x8 b, f32x4 c) {
  return __builtin_amdgcn_mfma_f32_16x16x32_bf16(a, b, c, 0, 0, 0);
}

// ---------------------------------------------------------------- cvt fp32->bf16
__global__ __launch_bounds__(256) void cvt_bf16_kernel(const float* __restrict__ src,
                                                       short* __restrict__ dst, int n4) {
  int i = blockIdx.x * 256 + threadIdx.x;
  if (i >= n4) return;
  f32x4 v = *(const f32x4*)(src + (size_t)i * 4);
  s16x4 o;
  o[0] = f2bf(v[0]); o[1] = f2bf(v[1]); o[2] = f2bf(v[2]); o[3] = f2bf(v[3]);
  *(s16x4*)(dst + (size_t)i * 4) = o;
}

// ---------------------------------------------------------------- init hidden
__global__ __launch_bounds__(256) void init_kernel(const float* __restrict__ ehid,
                                                   float* __restrict__ hidden,
                                                   short* __restrict__ xg) {
  int i = blockIdx.x * 256 + threadIdx.x;   // 32768
  float h = ehid[i];
  hidden[i] = h;
  int b = i >> 9, hh = i & 511;
  xg[b * 2048 + 1536 + hh] = f2bf(h);
}

// ---------------------------------------------------------------- enc_ua = enc @ ua^T  (M=8192,N=512,K=1024) -> bf16 out
__global__ __launch_bounds__(256) void enc_ua_kernel(const float* __restrict__ enc,
                                                     const float* __restrict__ ua,
                                                     short* __restrict__ enc_ua) {
  __shared__ short alds[64 * 264];
  int tid = threadIdx.x;
  int wv = tid >> 6, lane = tid & 63;
  int q = lane >> 4, ml = lane & 15;
  int m0 = blockIdx.x * 64;                 // 128 m-blocks
  int n0 = blockIdx.y * 128 + wv * 32;      // 4 n-blocks
  f32x4 acc[4][2];
  f32x4 zz = {0.f, 0.f, 0.f, 0.f};
#pragma unroll
  for (int a = 0; a < 4; a++) { acc[a][0] = zz; acc[a][1] = zz; }

  for (int kc = 0; kc < 4; kc++) {          // K chunks of 256
    __syncthreads();
    for (int i = tid; i < 4096; i += 256) { // 64 rows x 64 float4
      int m = i >> 6, kk = (i & 63) << 2;
      f32x4 v = *(const f32x4*)(enc + (size_t)(m0 + m) * 1024 + kc * 256 + kk);
      s16x4 o;
      o[0] = f2bf(v[0]); o[1] = f2bf(v[1]); o[2] = f2bf(v[2]); o[3] = f2bf(v[3]);
      *(s16x4*)(&alds[m * 264 + kk]) = o;
    }
    __syncthreads();
#pragma unroll
    for (int kt = 0; kt < 8; kt++) {
      int k = kt * 32 + q * 8;
      int gk = kc * 256 + k;
      s16x8 bf[2];
#pragma unroll
      for (int nf = 0; nf < 2; nf++) {
        const float* bp = ua + (size_t)(n0 + nf * 16 + ml) * 1024 + gk;
        f32x4 b0 = *(const f32x4*)bp, b1 = *(const f32x4*)(bp + 4);
        s16x8 t;
        t[0] = f2bf(b0[0]); t[1] = f2bf(b0[1]); t[2] = f2bf(b0[2]); t[3] = f2bf(b0[3]);
        t[4] = f2bf(b1[0]); t[5] = f2bf(b1[1]); t[6] = f2bf(b1[2]); t[7] = f2bf(b1[3]);
        bf[nf] = t;
      }
#pragma unroll
      for (int mt = 0; mt < 4; mt++) {
        s16x8 af = *(const s16x8*)(&alds[(mt * 16 + ml) * 264 + k]);
        acc[mt][0] = mfma16(af, bf[0], acc[mt][0]);
        acc[mt][1] = mfma16(af, bf[1], acc[mt][1]);
      }
    }
  }
#pragma unroll
  for (int nf = 0; nf < 2; nf++) {
    int n = n0 + nf * 16 + ml;
#pragma unroll
    for (int mt = 0; mt < 4; mt++)
#pragma unroll
      for (int r = 0; r < 4; r++) {
        int m = m0 + mt * 16 + q * 4 + r;
        enc_ua[(size_t)m * 512 + n] = f2bf(acc[mt][nf][r]);
      }
  }
}

// ---------------------------------------------------------------- prep: qv = h_bf16 @ wab^T (M=64,N=512,K=512) + emb gather
__global__ __launch_bounds__(256) void prep_kernel(const short* __restrict__ xg_h,  // xg (hidden bf16 at +1536)
                                                   const short* __restrict__ wab,
                                                   float* __restrict__ qv,
                                                   const float* __restrict__ embedding,
                                                   const int* __restrict__ target,
                                                   short* __restrict__ xg,
                                                   short* __restrict__ xf, int t) {
  int tid = threadIdx.x;
  int wv = tid >> 6, lane = tid & 63;
  int q = lane >> 4, ml = lane & 15;
  int n = blockIdx.x * 64 + wv * 16 + ml;   // 8 blocks -> 512
  f32x4 acc[4];
  f32x4 zz = {0.f, 0.f, 0.f, 0.f};
#pragma unroll
  for (int a = 0; a < 4; a++) acc[a] = zz;

#pragma unroll
  for (int kt = 0; kt < 16; kt++) {         // K = 512
    int k = kt * 32 + q * 8;
    s16x8 bfrag = *(const s16x8*)(wab + (size_t)n * 512 + k);
#pragma unroll
    for (int mt = 0; mt < 4; mt++) {
      s16x8 af = *(const s16x8*)(xg_h + (size_t)(mt * 16 + ml) * 2048 + 1536 + k);
      acc[mt] = mfma16(af, bfrag, acc[mt]);
    }
  }
#pragma unroll
  for (int mt = 0; mt < 4; mt++)
#pragma unroll
    for (int r = 0; r < 4; r++) {
      int b = mt * 16 + q * 4 + r;
      qv[(size_t)b * 512 + n] = acc[mt][r];
    }

  // embedding gather: 2048 threads total, 16 elems each
  int gid = blockIdx.x * 256 + tid;
#pragma unroll
  for (int it = 0; it < 16; it++) {
    int i = gid + it * 2048;                // [0, 32768)
    int b = i >> 9, h = i & 511;
    int tok = (t == 0) ? 2 : target[b * 30 + (t - 1)];
    short s = f2bf(embedding[(size_t)tok * 512 + h]);
    xg[b * 2048 + h] = s;
    xf[b * 2048 + h] = s;
  }
}

// ---------------------------------------------------------------- scores[b,s] = sum_h tanh(q[b,h]+enc_ua[b,s,h])*va[h]
__global__ __launch_bounds__(256) void score_kernel(const float* __restrict__ qv,
                                                    const float* __restrict__ va,
                                                    const short* __restrict__ enc_ua,
                                                    float* __restrict__ scores) {
  int b = blockIdx.x >> 3;
  int sg = blockIdx.x & 7;                  // 8 groups of 16 s
  int tid = threadIdx.x;
  int wv = tid >> 6, lane = tid & 63;
  __shared__ float qv_s[512];
  __shared__ float va_s[512];
  for (int i = tid; i < 512; i += 256) {
    qv_s[i] = qv[b * 512 + i];
    va_s[i] = va[i];
  }
  __syncthreads();
#pragma unroll
  for (int r = 0; r < 4; r++) {
    int s = sg * 16 + wv * 4 + r;
    const short* eu = enc_ua + ((size_t)b * 128 + s) * 512 + lane * 8;
    s16x8 e8 = *(const s16x8*)eu;
    float a = 0.f;
#pragma unroll
    for (int j = 0; j < 8; j++) {
      int h = lane * 8 + j;
      float e = qv_s[h] + bf2f(e8[j]);
      float ex = __expf(2.f * e);
      float th = 1.f - 2.f / (ex + 1.f);
      a += th * va_s[h];
    }
#pragma unroll
    for (int off = 32; off > 0; off >>= 1) a += __shfl_down(a, off);
    if (lane == 0) scores[b * 128 + s] = a;
  }
}

// ---------------------------------------------------------------- softmax (per-block redundant) + context slice
template <bool ENCB>
__global__ __launch_bounds__(256) void ctx_kernel(const float* __restrict__ scores,
                                                  const float* __restrict__ encf,
                                                  const short* __restrict__ encb,
                                                  short* __restrict__ xg,
                                                  short* __restrict__ xf) {
  int b = blockIdx.x, tid = threadIdx.x;
  __shared__ float p[128];
  __shared__ float red[128];
  if (tid < 128) { p[tid] = scores[b * 128 + tid]; red[tid] = p[tid]; }
  __syncthreads();
  for (int st = 64; st >= 1; st >>= 1) {
    if (tid < st) red[tid] = fmaxf(red[tid], red[tid + st]);
    __syncthreads();
  }
  float mx = red[0];
  __syncthreads();
  if (tid < 128) { float e = __expf(p[tid] - mx); p[tid] = e; red[tid] = e; }
  __syncthreads();
  for (int st = 64; st >= 1; st >>= 1) {
    if (tid < st) red[tid] += red[tid + st];
    __syncthreads();
  }
  float inv = 1.f / red[0];
  __syncthreads();
  if (tid < 128) p[tid] *= inv;
  __syncthreads();

  int d = blockIdx.y * 256 + tid;           // [0,1024)
  float a = 0.f;
  if (ENCB) {
    const short* ep = encb + (size_t)b * 128 * 1024 + d;
#pragma unroll 4
    for (int s = 0; s < 128; s++) a += p[s] * bf2f(ep[(size_t)s * 1024]);
  } else {
    const float* ep = encf + (size_t)b * 128 * 1024 + d;
#pragma unroll 4
    for (int s = 0; s < 128; s++) a += p[s] * ep[(size_t)s * 1024];
  }
  short c = f2bf(a);
  xg[b * 2048 + 512 + d] = c;
  xf[b * 2048 + 1024 + d] = c;
}

// ---------------------------------------------------------------- GRU GEMMs
__global__ __launch_bounds__(256) void gru_gemm_kernel(const short* __restrict__ xg,
                                                       const short* __restrict__ wihb,
                                                       const short* __restrict__ whhb,
                                                       float* __restrict__ gi,
                                                       float* __restrict__ gh) {
  int tid = threadIdx.x;
  int wv = tid >> 6, lane = tid & 63;
  int q = lane >> 4, ml = lane & 15;
  int n = blockIdx.x * 64 + wv * 16 + ml;   // 24 blocks -> 1536
  f32x4 acci[4], acch[4];
  f32x4 zz = {0.f, 0.f, 0.f, 0.f};
#pragma unroll
  for (int a = 0; a < 4; a++) { acci[a] = zz; acch[a] = zz; }

  for (int kt = 0; kt < 48; kt++) {         // K = 1536
    int k = kt * 32 + q * 8;
    s16x8 bfrag = *(const s16x8*)(wihb + (size_t)n * 1536 + k);
#pragma unroll
    for (int mt = 0; mt < 4; mt++) {
      s16x8 af = *(const s16x8*)(xg + (size_t)(mt * 16 + ml) * 2048 + k);
      acci[mt] = mfma16(af, bfrag, acci[mt]);
    }
  }
  for (int kt = 0; kt < 16; kt++) {         // K = 512 (hidden)
    int k = kt * 32 + q * 8;
    s16x8 bfrag = *(const s16x8*)(whhb + (size_t)n * 512 + k);
#pragma unroll
    for (int mt = 0; mt < 4; mt++) {
      s16x8 af = *(const s16x8*)(xg + (size_t)(mt * 16 + ml) * 2048 + 1536 + k);
      acch[mt] = mfma16(af, bfrag, acch[mt]);
    }
  }
#pragma unroll
  for (int mt = 0; mt < 4; mt++)
#pragma unroll
    for (int r = 0; r < 4; r++) {
      int b = mt * 16 + q * 4 + r;
      gi[(size_t)b * 1536 + n] = acci[mt][r];
      gh[(size_t)b * 1536 + n] = acch[mt][r];
    }
}

// ---------------------------------------------------------------- gates (fp32)
__global__ __launch_bounds__(256) void gates_kernel(const float* __restrict__ gi,
                                                    const float* __restrict__ gh,
                                                    const float* __restrict__ bih,
                                                    const float* __restrict__ bhh,
                                                    float* __restrict__ hidden,
                                                    short* __restrict__ xg,
                                                    short* __restrict__ xf) {
  int i = blockIdx.x * 256 + threadIdx.x;   // 32768
  int b = i >> 9, h = i & 511;
  const float* gib = gi + (size_t)b * 1536;
  const float* ghb = gh + (size_t)b * 1536;
  float ir = gib[h] + bih[h];
  float iz = gib[512 + h] + bih[512 + h];
  float in_ = gib[1024 + h] + bih[1024 + h];
  float hr = ghb[h] + bhh[h];
  float hz = ghb[512 + h] + bhh[512 + h];
  float hn = ghb[1024 + h] + bhh[1024 + h];
  float r = 1.f / (1.f + __expf(-(ir + hr)));
  float z = 1.f / (1.f + __expf(-(iz + hz)));
  float nx = in_ + r * hn;
  float ex = __expf(2.f * nx);
  float n = 1.f - 2.f / (ex + 1.f);
  float hnew = (1.f - z) * n + z * hidden[i];
  hidden[i] = hnew;
  short hb = f2bf(hnew);
  xg[b * 2048 + 1536 + h] = hb;
  xf[b * 2048 + 512 + h] = hb;
}

// ---------------------------------------------------------------- fc: logits = xf @ fc_w^T + fc_b  (M=64,N=32000,K=2048)
template <bool PRE>
__global__ __launch_bounds__(256) void fc_kernel(const short* __restrict__ xf,
                                                 const short* __restrict__ fcwb,
                                                 const float* __restrict__ fcwf,
                                                 const float* __restrict__ fcb,
                                                 float* __restrict__ out, int t) {
  __shared__ short alds[64 * 264];
  int tid = threadIdx.x;
  int wv = tid >> 6, lane = tid & 63;
  int q = lane >> 4, ml = lane & 15;
  int n0 = blockIdx.x * 128 + wv * 32;      // 250 blocks
  f32x4 acc[4][2];
  f32x4 zz = {0.f, 0.f, 0.f, 0.f};
#pragma unroll
  for (int a = 0; a < 4; a++) { acc[a][0] = zz; acc[a][1] = zz; }

  for (int kc = 0; kc < 8; kc++) {          // K chunks of 256
    __syncthreads();
    for (int i = tid; i < 2048; i += 256) { // 64 rows x 32 x (8 bf16)
      int m = i >> 5, kk = (i & 31) << 3;
      *(s16x8*)(&alds[m * 264 + kk]) = *(const s16x8*)(xf + (size_t)m * 2048 + kc * 256 + kk);
    }
    __syncthreads();
#pragma unroll
    for (int kt = 0; kt < 8; kt++) {
      int k = kt * 32 + q * 8;
      int gk = kc * 256 + k;
      s16x8 bf0, bf1;
      if (PRE) {
        bf0 = *(const s16x8*)(fcwb + (size_t)(n0 + ml) * 2048 + gk);
        bf1 = *(const s16x8*)(fcwb + (size_t)(n0 + 16 + ml) * 2048 + gk);
      } else {
        const float* p0 = fcwf + (size_t)(n0 + ml) * 2048 + gk;
        const float* p1 = fcwf + (size_t)(n0 + 16 + ml) * 2048 + gk;
        f32x4 a0 = *(const f32x4*)p0, a1 = *(const f32x4*)(p0 + 4);
        f32x4 b0 = *(const f32x4*)p1, b1 = *(const f32x4*)(p1 + 4);
        bf0[0] = f2bf(a0[0]); bf0[1] = f2bf(a0[1]); bf0[2] = f2bf(a0[2]); bf0[3] = f2bf(a0[3]);
        bf0[4] = f2bf(a1[0]); bf0[5] = f2bf(a1[1]); bf0[6] = f2bf(a1[2]); bf0[7] = f2bf(a1[3]);
        bf1[0] = f2bf(b0[0]); bf1[1] = f2bf(b0[1]); bf1[2] = f2bf(b0[2]); bf1[3] = f2bf(b0[3]);
        bf1[4] = f2bf(b1[0]); bf1[5] = f2bf(b1[1]); bf1[6] = f2bf(b1[2]); bf1[7] = f2bf(b1[3]);
      }
#pragma unroll
      for (int mt = 0; mt < 4; mt++) {
        s16x8 af = *(const s16x8*)(&alds[(mt * 16 + ml) * 264 + k]);
        acc[mt][0] = mfma16(af, bf0, acc[mt][0]);
        acc[mt][1] = mfma16(af, bf1, acc[mt][1]);
      }
    }
  }
#pragma unroll
  for (int nf = 0; nf < 2; nf++) {
    int v = n0 + nf * 16 + ml;
    float bias = fcb[v];
#pragma unroll
    for (int mt = 0; mt < 4; mt++)
#pragma unroll
      for (int r = 0; r < 4; r++) {
        int b = mt * 16 + q * 4 + r;
        out[((size_t)b * T_ + t) * V_ + v] = acc[mt][nf][r] + bias;
      }
  }
}

// ---------------------------------------------------------------- per-step log_softmax over V
__global__ __launch_bounds__(256) void finalize_kernel(float* __restrict__ out, int t) {
  int b = blockIdx.x, tid = threadIdx.x;
  float* row = out + ((size_t)b * T_ + t) * V_;
  __shared__ float red[256];
  float mx = -3.4e38f;
  for (int i = tid; i < 8000; i += 256) {
    f32x4 v = *(const f32x4*)(row + i * 4);
    mx = fmaxf(mx, fmaxf(fmaxf(v[0], v[1]), fmaxf(v[2], v[3])));
  }
  red[tid] = mx; __syncthreads();
  for (int st = 128; st >= 1; st >>= 1) {
    if (tid < st) red[tid] = fmaxf(red[tid], red[tid + st]);
    __syncthreads();
  }
  mx = red[0]; __syncthreads();
  float sm = 0.f;
  for (int i = tid; i < 8000; i += 256) {
    f32x4 v = *(const f32x4*)(row + i * 4);
    sm += __expf(v[0] - mx) + __expf(v[1] - mx) + __expf(v[2] - mx) + __expf(v[3] - mx);
  }
  red[tid] = sm; __syncthreads();
  for (int st = 128; st >= 1; st >>= 1) {
    if (tid < st) red[tid] += red[tid + st];
    __syncthreads();
  }
  float lse = mx + __logf(red[0]);
  for (int i = tid; i < 8000; i += 256) {
    f32x4 v = *(const f32x4*)(row + i * 4);
    v[0] -= lse; v[1] -= lse; v[2] -= lse; v[3] -= lse;
    *(f32x4*)(row + i * 4) = v;
  }
}

// ================================================================ host
extern "C" void kernel_launch(void* const* d_in, const int* in_sizes, int n_in,
                              void* d_out, int out_size, void* d_ws, size_t ws_size,
                              hipStream_t stream) {
  const float* enc  = (const float*)d_in[0];
  const float* ehid = (const float*)d_in[1];
  const int*   tgt  = (const int*)  d_in[2];
  const float* emb  = (const float*)d_in[3];
  const float* wa   = (const float*)d_in[4];
  const float* ua   = (const float*)d_in[5];
  const float* va   = (const float*)d_in[6];
  const float* wih  = (const float*)d_in[7];
  const float* whh  = (const float*)d_in[8];
  const float* bih  = (const float*)d_in[9];
  const float* bhh  = (const float*)d_in[10];
  const float* fcw  = (const float*)d_in[11];
  const float* fcb  = (const float*)d_in[12];
  float* out = (float*)d_out;

  const size_t SZ_FCWB = (size_t)V_ * KF_ * 2;        // 131 MB
  const size_t SZ_ENCB = (size_t)B_ * S_ * 1024 * 2;  // 16.8 MB
  char* ws = (char*)d_ws;
  size_t off = 0;
  auto take = [&](size_t bytes) -> char* {
    char* p = ws + off;
    off = (off + bytes + 255) & ~(size_t)255;
    return p;
  };
  // small-buffer footprint (everything except fcwb, encb)
  size_t small_need;
  {
    size_t o = 0;
    auto sim = [&](size_t bb) { o = (o + bb + 255) & ~(size_t)255; };
    sim((size_t)B_ * S_ * H_ * 2);  // enc_ua bf16
    sim((size_t)3 * H_ * KX_ * 2);  // wihb
    sim((size_t)3 * H_ * H_ * 2);   // whhb
    sim((size_t)H_ * H_ * 2);       // wab
    sim((size_t)B_ * H_ * 4);       // hidden
    sim((size_t)B_ * H_ * 4);       // qv
    sim((size_t)B_ * S_ * 4);       // scores
    sim((size_t)B_ * KF_ * 2);      // xg
    sim((size_t)B_ * KF_ * 2);      // xf
    sim((size_t)B_ * 3 * H_ * 4);   // gi
    sim((size_t)B_ * 3 * H_ * 4);   // gh
    small_need = o;
  }
  bool PRE  = ws_size >= SZ_FCWB + small_need + 512;
  bool ENCB = ws_size >= SZ_FCWB + SZ_ENCB + small_need + 1024;

  short* fcwb = PRE ? (short*)take(SZ_FCWB) : nullptr;
  short* encb = ENCB ? (short*)take(SZ_ENCB) : nullptr;
  short* enc_ua = (short*)take((size_t)B_ * S_ * H_ * 2);
  short* wihb   = (short*)take((size_t)3 * H_ * KX_ * 2);
  short* whhb   = (short*)take((size_t)3 * H_ * H_ * 2);
  short* wab    = (short*)take((size_t)H_ * H_ * 2);
  float* hidden = (float*)take((size_t)B_ * H_ * 4);
  float* qv     = (float*)take((size_t)B_ * H_ * 4);
  float* scores = (float*)take((size_t)B_ * S_ * 4);
  short* xg     = (short*)take((size_t)B_ * KF_ * 2);
  short* xf     = (short*)take((size_t)B_ * KF_ * 2);
  float* gi     = (float*)take((size_t)B_ * 3 * H_ * 4);
  float* gh     = (float*)take((size_t)B_ * 3 * H_ * 4);

  if (PRE)
    cvt_bf16_kernel<<<(V_ * KF_ / 4 + 255) / 256, 256, 0, stream>>>(fcw, fcwb, V_ * KF_ / 4);
  if (ENCB)
    cvt_bf16_kernel<<<(B_ * S_ * 1024 / 4 + 255) / 256, 256, 0, stream>>>(enc, encb, B_ * S_ * 1024 / 4);
  cvt_bf16_kernel<<<(3 * H_ * KX_ / 4 + 255) / 256, 256, 0, stream>>>(wih, wihb, 3 * H_ * KX_ / 4);
  cvt_bf16_kernel<<<(3 * H_ * H_ / 4 + 255) / 256, 256, 0, stream>>>(whh, whhb, 3 * H_ * H_ / 4);
  cvt_bf16_kernel<<<(H_ * H_ / 4 + 255) / 256, 256, 0, stream>>>(wa, wab, H_ * H_ / 4);
  init_kernel<<<(B_ * H_) / 256, 256, 0, stream>>>(ehid, hidden, xg);
  enc_ua_kernel<<<dim3(128, 4), 256, 0, stream>>>(enc, ua, enc_ua);

  for (int t = 0; t < T_; t++) {
    prep_kernel<<<8, 256, 0, stream>>>(xg, wab, qv, emb, tgt, xg, xf, t);
    score_kernel<<<B_ * 8, 256, 0, stream>>>(qv, va, enc_ua, scores);
    if (ENCB)
      ctx_kernel<true><<<dim3(B_, 4), 256, 0, stream>>>(scores, enc, encb, xg, xf);
    else
      ctx_kernel<false><<<dim3(B_, 4), 256, 0, stream>>>(scores, enc, encb, xg, xf);
    gru_gemm_kernel<<<24, 256, 0, stream>>>(xg, wihb, whhb, gi, gh);
    gates_kernel<<<(B_ * H_) / 256, 256, 0, stream>>>(gi, gh, bih, bhh, hidden, xg, xf);
    if (PRE)
      fc_kernel<true><<<V_ / 128, 256, 0, stream>>>(xf, fcwb, fcw, fcb, out, t);
    else
      fc_kernel<false><<<V_ / 128, 256, 0, stream>>>(xf, fcwb, fcw, fcb, out, t);
    finalize_kernel<<<B_, 256, 0, stream>>>(out, t);
  }
}